// Round 1
// baseline (5126.881 us; speedup 1.0000x reference)
//
#include <hip/hip_runtime.h>
#include <math.h>

#define RFL(x) __builtin_amdgcn_readfirstlane(x)

// ---------------- degree / norm ----------------

__global__ __launch_bounds__(256) void k_fill_deg(float* deg, int N) {
  int t = blockIdx.x * 256 + threadIdx.x;
  if (t < N) deg[t] = 1.0f;  // self-loop
}

__global__ __launch_bounds__(256) void k_count_deg(const int* __restrict__ dst, float* deg, int E) {
  int stride = gridDim.x * blockDim.x;
  for (int e = blockIdx.x * blockDim.x + threadIdx.x; e < E; e += stride)
    atomicAdd(&deg[dst[e]], 1.0f);
}

__global__ __launch_bounds__(256) void k_dinv(float* deg, int N) {
  int t = blockIdx.x * 256 + threadIdx.x;
  if (t < N) deg[t] = rsqrtf(deg[t]);  // deg >= 1 always
}

__global__ __launch_bounds__(256) void k_norm(const int* __restrict__ src, const int* __restrict__ dst,
                                              const float* __restrict__ dinv, float* __restrict__ nrm, int E) {
  int stride = gridDim.x * blockDim.x;
  for (int e = blockIdx.x * blockDim.x + threadIdx.x; e < E; e += stride)
    nrm[e] = dinv[src[e]] * dinv[dst[e]];
}

// ---------------- W_c = W_out @ W1, b_c = b_out @ W1 ----------------
// W_out (64,128), W1 (128,128) -> Wc (64,128); bout (128) -> bc (128)

__global__ __launch_bounds__(256) void k_wc(const float* __restrict__ Wout, const float* __restrict__ bout,
                                            const float* __restrict__ W1, float* __restrict__ Wc,
                                            float* __restrict__ bc) {
  int t = blockIdx.x * 256 + threadIdx.x;
  if (t >= 65 * 128) return;
  int h = t >> 7, o = t & 127;
  const float* row = (h < 64) ? (Wout + h * 128) : bout;
  float a = 0.f;
  for (int d = 0; d < 128; ++d) a += row[d] * W1[d * 128 + o];
  if (h < 64) Wc[h * 128 + o] = a;
  else bc[o] = a;
}

// ---------------- attention pooling ----------------
// one wave per node; lane l holds W_embed[:, l] in regs; X rows via wave-uniform
// (scalar) loads; online softmax (running max m, denom Zs, weighted sum P).

__global__ __launch_bounds__(256) void k_pool(const float* __restrict__ X, const int* __restrict__ mask,
                                              const float* __restrict__ WE, const float* __restrict__ bE,
                                              const float* __restrict__ WA, const float* __restrict__ bA,
                                              float* __restrict__ pz, int N) {
  const int lane = threadIdx.x & 63;
  const int node = RFL(blockIdx.x * 4 + (threadIdx.x >> 6));
  if (node >= N) return;

  float w[128];
#pragma unroll
  for (int d = 0; d < 128; ++d) w[d] = WE[d * 64 + lane];
  const float be = bE[lane];
  const float wa = WA[lane];
  const float ba = bA[0];

  const float* __restrict__ xb = X + (size_t)node * (20 * 128);
  const int* __restrict__ mr = mask + node * 20;

  float m = -INFINITY, Zs = 0.f, P = 0.f;
  for (int s = 0; s < 20; ++s) {
    const float* __restrict__ xr = xb + s * 128;
    float p0 = 0.f, p1 = 0.f, p2 = 0.f, p3 = 0.f;
#pragma unroll
    for (int d = 0; d < 128; d += 4) {
      p0 += xr[d + 0] * w[d + 0];
      p1 += xr[d + 1] * w[d + 1];
      p2 += xr[d + 2] * w[d + 2];
      p3 += xr[d + 3] * w[d + 3];
    }
    float z = fmaxf(be + ((p0 + p1) + (p2 + p3)), 0.f);  // z[s, lane]
    float sc = z * wa;
#pragma unroll
    for (int off = 32; off > 0; off >>= 1) sc += __shfl_xor(sc, off, 64);
    sc += ba;  // score[s], all lanes
    if (mr[s] != 0) {
      if (sc > m) {
        float scale = __expf(m - sc);  // first iter: exp(-inf)=0
        Zs = Zs * scale + 1.f;
        P = P * scale + z;
        m = sc;
      } else {
        float p = __expf(sc - m);
        Zs += p;
        P += p * z;
      }
    }
  }
  pz[(size_t)node * 64 + lane] = P / Zs;
}

// ---------------- h1 = pz @ Wc + bc ; x1 = h1 * dinv^2 (self-loop init) ----------------
// wave per row; lane holds Wc[:, lane] and Wc[:, lane+64] in regs; row via scalar loads.

__global__ __launch_bounds__(256) void k_gemm1(const float* __restrict__ pz, const float* __restrict__ Wc,
                                               const float* __restrict__ bc, const float* __restrict__ dinv,
                                               float* __restrict__ h1, float* __restrict__ x1, int N) {
  const int lane = threadIdx.x & 63;
  float w0[64], w1[64];
#pragma unroll
  for (int d = 0; d < 64; ++d) {
    w0[d] = Wc[d * 128 + lane];
    w1[d] = Wc[d * 128 + 64 + lane];
  }
  const float b0 = bc[lane], b1v = bc[64 + lane];
  const int nw = (gridDim.x * blockDim.x) >> 6;
  const int w_id = RFL((blockIdx.x * blockDim.x + threadIdx.x) >> 6);
  for (int r = w_id; r < N; r += nw) {
    const float* __restrict__ xr = pz + (size_t)r * 64;
    float a0 = 0.f, a1 = 0.f, a2 = 0.f, a3 = 0.f;
#pragma unroll
    for (int d = 0; d < 64; d += 2) {
      a0 += xr[d] * w0[d];
      a1 += xr[d] * w1[d];
      a2 += xr[d + 1] * w0[d + 1];
      a3 += xr[d + 1] * w1[d + 1];
    }
    float v0 = b0 + a0 + a2, v1 = b1v + a1 + a3;
    float di = dinv[r];
    float d2 = di * di;
    size_t o = (size_t)r * 128 + lane;
    h1[o] = v0;
    h1[o + 64] = v1;
    x1[o] = v0 * d2;
    x1[o + 64] = v1 * d2;
  }
}

// ---------------- h2 = relu(x1 + b1) @ W2 ; x2 = h2 * dinv^2 ----------------
// wave per row; lane l holds W2[:, l&31] fully (lanes 32..63 duplicate; stores guarded).

__global__ __launch_bounds__(256) void k_gemm2(const float* __restrict__ x1, const float* __restrict__ b1,
                                               const float* __restrict__ W2, const float* __restrict__ dinv,
                                               float* __restrict__ h2, float* __restrict__ x2, int N) {
  const int lane = threadIdx.x & 63;
  const int col = lane & 31;
  float w[128];
#pragma unroll
  for (int d = 0; d < 128; ++d) w[d] = W2[d * 32 + col];
  const int nw = (gridDim.x * blockDim.x) >> 6;
  const int w_id = RFL((blockIdx.x * blockDim.x + threadIdx.x) >> 6);
  for (int r = w_id; r < N; r += nw) {
    const float* __restrict__ xr = x1 + (size_t)r * 128;
    float a0 = 0.f, a1 = 0.f, a2 = 0.f, a3 = 0.f;
#pragma unroll
    for (int d = 0; d < 128; d += 4) {
      a0 += fmaxf(xr[d + 0] + b1[d + 0], 0.f) * w[d + 0];
      a1 += fmaxf(xr[d + 1] + b1[d + 1], 0.f) * w[d + 1];
      a2 += fmaxf(xr[d + 2] + b1[d + 2], 0.f) * w[d + 2];
      a3 += fmaxf(xr[d + 3] + b1[d + 3], 0.f) * w[d + 3];
    }
    if (lane < 32) {
      float v = (a0 + a1) + (a2 + a3);
      float di = dinv[r];
      h2[(size_t)r * 32 + col] = v;
      x2[(size_t)r * 32 + col] = v * di * di;
    }
  }
}

// ---------------- edge scatter, layer 1: x1[d] += h1[s] * nrm[e] ----------------
// 4 lanes per edge -> 16 independent edges in flight per wave-iteration.

__global__ __launch_bounds__(256) void k_scatter1(const int* __restrict__ src, const int* __restrict__ dst,
                                                  const float* __restrict__ nrm, const float* __restrict__ h1,
                                                  float* __restrict__ x1, int E) {
  const int lane = threadIdx.x & 63;
  const int g = lane >> 2, q = lane & 3;
  const long long nw = (long long)((gridDim.x * blockDim.x) >> 6);
  const long long wid = (long long)((blockIdx.x * blockDim.x + threadIdx.x) >> 6);
  for (long long base = wid * 16; base < E; base += nw * 16) {
    long long e = base + g;
    int s = 0, d = 0;
    float wgt = 0.f;
    if (e < E) { s = src[e]; d = dst[e]; wgt = nrm[e]; }
    const float* __restrict__ hp = h1 + (size_t)s * 128 + q * 4;
    float* __restrict__ xp = x1 + (size_t)d * 128 + q * 4;
#pragma unroll
    for (int j = 0; j < 8; ++j) {
      float4 v = *(const float4*)(hp + j * 16);
      atomicAdd(xp + j * 16 + 0, v.x * wgt);
      atomicAdd(xp + j * 16 + 1, v.y * wgt);
      atomicAdd(xp + j * 16 + 2, v.z * wgt);
      atomicAdd(xp + j * 16 + 3, v.w * wgt);
    }
  }
}

// ---------------- edge scatter, layer 2: x2[d] += h2[s] * nrm[e] (32 feats) ----------------
// 2 lanes per edge -> 32 edges per wave-iteration.

__global__ __launch_bounds__(256) void k_scatter2(const int* __restrict__ src, const int* __restrict__ dst,
                                                  const float* __restrict__ nrm, const float* __restrict__ h2,
                                                  float* __restrict__ x2, int E) {
  const int lane = threadIdx.x & 63;
  const int g = lane >> 1, q = lane & 1;
  const long long nw = (long long)((gridDim.x * blockDim.x) >> 6);
  const long long wid = (long long)((blockIdx.x * blockDim.x + threadIdx.x) >> 6);
  for (long long base = wid * 32; base < E; base += nw * 32) {
    long long e = base + g;
    int s = 0, d = 0;
    float wgt = 0.f;
    if (e < E) { s = src[e]; d = dst[e]; wgt = nrm[e]; }
    const float* __restrict__ hp = h2 + (size_t)s * 32 + q * 4;
    float* __restrict__ xp = x2 + (size_t)d * 32 + q * 4;
#pragma unroll
    for (int j = 0; j < 4; ++j) {
      float4 v = *(const float4*)(hp + j * 8);
      atomicAdd(xp + j * 8 + 0, v.x * wgt);
      atomicAdd(xp + j * 8 + 1, v.y * wgt);
      atomicAdd(xp + j * 8 + 2, v.z * wgt);
      atomicAdd(xp + j * 8 + 3, v.w * wgt);
    }
  }
}

// ---------------- query MLP ----------------
// logits = relu(relu(x2[qidx] + b2) @ Wm1 + bm1) @ Wm2 + bm2

__global__ __launch_bounds__(256) void k_mlp(const int* __restrict__ qidx, const float* __restrict__ x2,
                                             const float* __restrict__ b2, const float* __restrict__ Wm1,
                                             const float* __restrict__ bm1, const float* __restrict__ Wm2,
                                             const float* __restrict__ bm2, float* __restrict__ out, int B) {
  int t = blockIdx.x * 256 + threadIdx.x;
  if (t >= B) return;
  int n = qidx[t];
  float qv[32];
#pragma unroll
  for (int k = 0; k < 32; ++k) qv[k] = fmaxf(x2[(size_t)n * 32 + k] + b2[k], 0.f);
  float acc = bm2[0];
  for (int j = 0; j < 64; ++j) {
    float h = bm1[j];
#pragma unroll
    for (int k = 0; k < 32; ++k) h += qv[k] * Wm1[k * 64 + j];
    acc += fmaxf(h, 0.f) * Wm2[j];
  }
  out[t] = acc;
}

// ---------------- launcher ----------------

extern "C" void kernel_launch(void* const* d_in, const int* in_sizes, int n_in,
                              void* d_out, int out_size, void* d_ws, size_t ws_size,
                              hipStream_t stream) {
  const float* X    = (const float*)d_in[0];
  const int*   mask = (const int*)d_in[1];
  const int*   ei   = (const int*)d_in[2];
  const int*   qidx = (const int*)d_in[3];
  const float* WE   = (const float*)d_in[4];
  const float* bE   = (const float*)d_in[5];
  const float* WA   = (const float*)d_in[6];
  const float* bA   = (const float*)d_in[7];
  const float* Wout = (const float*)d_in[8];
  const float* bout = (const float*)d_in[9];
  const float* W1   = (const float*)d_in[10];
  const float* b1   = (const float*)d_in[11];
  const float* W2   = (const float*)d_in[12];
  const float* b2   = (const float*)d_in[13];
  const float* Wm1  = (const float*)d_in[14];
  const float* bm1  = (const float*)d_in[15];
  const float* Wm2  = (const float*)d_in[16];
  const float* bm2  = (const float*)d_in[17];

  const int N = in_sizes[1] / 20;
  const int E = in_sizes[2] / 2;
  const int B = in_sizes[3];
  const int* src  = ei;
  const int* dstp = ei + E;

  float* ws  = (float*)d_ws;
  float* deg = ws;                                 // N floats (becomes dinv)
  float* Wc  = deg + (((size_t)N + 63) & ~(size_t)63);
  float* bc  = Wc + 8192;
  float* nrm = bc + 128;                           // E floats
  float* pzb = nrm + (((size_t)E + 63) & ~(size_t)63);  // N*64
  float* h1  = pzb + (size_t)N * 64;               // N*128
  float* x1  = h1 + (size_t)N * 128;               // N*128
  float* h2  = pzb;                                // reuse pz region (dead after gemm1)
  float* x2  = pzb + (size_t)N * 32;

  k_fill_deg<<<(N + 255) / 256, 256, 0, stream>>>(deg, N);
  k_count_deg<<<1024, 256, 0, stream>>>(dstp, deg, E);
  k_dinv<<<(N + 255) / 256, 256, 0, stream>>>(deg, N);
  k_wc<<<33, 256, 0, stream>>>(Wout, bout, W1, Wc, bc);
  k_norm<<<1024, 256, 0, stream>>>(src, dstp, deg, nrm, E);
  k_pool<<<(N + 3) / 4, 256, 0, stream>>>(X, mask, WE, bE, WA, bA, pzb, N);
  k_gemm1<<<1024, 256, 0, stream>>>(pzb, Wc, bc, deg, h1, x1, N);
  k_scatter1<<<2048, 256, 0, stream>>>(src, dstp, nrm, h1, x1, E);
  k_gemm2<<<1024, 256, 0, stream>>>(x1, b1, W2, deg, h2, x2, N);
  k_scatter2<<<1024, 256, 0, stream>>>(src, dstp, nrm, h2, x2, E);
  k_mlp<<<(B + 255) / 256, 256, 0, stream>>>(qidx, x2, b2, Wm1, bm1, Wm2, bm2, (float*)d_out, B);
}

// Round 2
// 1443.215 us; speedup vs baseline: 3.5524x; 3.5524x over previous
//
#include <hip/hip_runtime.h>
#include <math.h>

#define RFL(x) __builtin_amdgcn_readfirstlane(x)

// ---------------- degree histogram (int) ----------------

__global__ __launch_bounds__(256) void k_zero(int* p, int n) {
  int t = blockIdx.x * 256 + threadIdx.x;
  if (t < n) p[t] = 0;
}

__global__ __launch_bounds__(256) void k_count(const int* __restrict__ dst, int* cnt, int E) {
  int stride = gridDim.x * blockDim.x;
  for (int e = blockIdx.x * blockDim.x + threadIdx.x; e < E; e += stride)
    atomicAdd(&cnt[dst[e]], 1);
}

__global__ __launch_bounds__(256) void k_dinv(const int* __restrict__ cnt, float* dinv, int N) {
  int t = blockIdx.x * 256 + threadIdx.x;
  if (t < N) dinv[t] = rsqrtf((float)cnt[t] + 1.0f);  // +1 self-loop
}

// ---------------- exclusive scan: cnt -> row_start ----------------

__global__ __launch_bounds__(256) void k_scan1(const int* __restrict__ cnt, int* __restrict__ row,
                                               int* __restrict__ partial, int N) {
  __shared__ int sm[256];
  int t = threadIdx.x, g = blockIdx.x * 256 + t;
  int v = (g < N) ? cnt[g] : 0;
  sm[t] = v;
  __syncthreads();
#pragma unroll
  for (int off = 1; off < 256; off <<= 1) {
    int x = 0;
    if (t >= off) x = sm[t - off];
    __syncthreads();
    if (t >= off) sm[t] += x;
    __syncthreads();
  }
  if (g < N) row[g] = sm[t] - v;  // exclusive within block
  if (t == 255) partial[blockIdx.x] = sm[255];
}

__global__ __launch_bounds__(256) void k_scan2(int* __restrict__ partial, int P) {
  __shared__ int sm[256];
  int t = threadIdx.x;
  int carry = 0;
  for (int base = 0; base < P; base += 256) {
    int idx = base + t;
    int v = (idx < P) ? partial[idx] : 0;
    sm[t] = v;
    __syncthreads();
#pragma unroll
    for (int off = 1; off < 256; off <<= 1) {
      int x = 0;
      if (t >= off) x = sm[t - off];
      __syncthreads();
      if (t >= off) sm[t] += x;
      __syncthreads();
    }
    if (idx < P) partial[idx] = carry + sm[t] - v;  // exclusive
    int tot = sm[255];
    __syncthreads();
    carry += tot;
  }
}

__global__ __launch_bounds__(256) void k_scan3(int* __restrict__ row, const int* __restrict__ partial,
                                               int* __restrict__ cursor, int N) {
  int g = blockIdx.x * 256 + threadIdx.x;
  if (g < N) {
    int v = row[g] + partial[blockIdx.x];
    row[g] = v;
    cursor[g] = v;
  }
}

// ---------------- edge placement: dst-sorted (src, norm) ----------------

__global__ __launch_bounds__(256) void k_edge_fill(const int* __restrict__ src, const int* __restrict__ dst,
                                                   const float* __restrict__ dinv, int* __restrict__ cursor,
                                                   int* __restrict__ esrc, float* __restrict__ enrm, int E) {
  int stride = gridDim.x * blockDim.x;
  for (int e = blockIdx.x * blockDim.x + threadIdx.x; e < E; e += stride) {
    int s = src[e], d = dst[e];
    int pos = atomicAdd(&cursor[d], 1);
    esrc[pos] = s;
    enrm[pos] = dinv[s] * dinv[d];
  }
}

// ---------------- W_c = W_out @ W1, b_c = b_out @ W1 ----------------

__global__ __launch_bounds__(256) void k_wc(const float* __restrict__ Wout, const float* __restrict__ bout,
                                            const float* __restrict__ W1, float* __restrict__ Wc,
                                            float* __restrict__ bc) {
  int t = blockIdx.x * 256 + threadIdx.x;
  if (t >= 65 * 128) return;
  int h = t >> 7, o = t & 127;
  const float* row = (h < 64) ? (Wout + h * 128) : bout;
  float a = 0.f;
  for (int d = 0; d < 128; ++d) a += row[d] * W1[d * 128 + o];
  if (h < 64) Wc[h * 128 + o] = a;
  else bc[o] = a;
}

// ---------------- attention pooling ----------------

__global__ __launch_bounds__(256) void k_pool(const float* __restrict__ X, const int* __restrict__ mask,
                                              const float* __restrict__ WE, const float* __restrict__ bE,
                                              const float* __restrict__ WA, const float* __restrict__ bA,
                                              float* __restrict__ pz, int N) {
  const int lane = threadIdx.x & 63;
  const int node = RFL(blockIdx.x * 4 + (threadIdx.x >> 6));
  if (node >= N) return;

  float w[128];
#pragma unroll
  for (int d = 0; d < 128; ++d) w[d] = WE[d * 64 + lane];
  const float be = bE[lane];
  const float wa = WA[lane];
  const float ba = bA[0];

  const float* __restrict__ xb = X + (size_t)node * (20 * 128);
  const int* __restrict__ mr = mask + node * 20;

  float m = -INFINITY, Zs = 0.f, P = 0.f;
  for (int s = 0; s < 20; ++s) {
    const float* __restrict__ xr = xb + s * 128;
    float p0 = 0.f, p1 = 0.f, p2 = 0.f, p3 = 0.f;
#pragma unroll
    for (int d = 0; d < 128; d += 4) {
      p0 += xr[d + 0] * w[d + 0];
      p1 += xr[d + 1] * w[d + 1];
      p2 += xr[d + 2] * w[d + 2];
      p3 += xr[d + 3] * w[d + 3];
    }
    float z = fmaxf(be + ((p0 + p1) + (p2 + p3)), 0.f);  // z[s, lane]
    float sc = z * wa;
#pragma unroll
    for (int off = 32; off > 0; off >>= 1) sc += __shfl_xor(sc, off, 64);
    sc += ba;  // score[s], all lanes
    if (mr[s] != 0) {
      if (sc > m) {
        float scale = __expf(m - sc);  // first iter: exp(-inf)=0
        Zs = Zs * scale + 1.f;
        P = P * scale + z;
        m = sc;
      } else {
        float p = __expf(sc - m);
        Zs += p;
        P += p * z;
      }
    }
  }
  pz[(size_t)node * 64 + lane] = P / Zs;
}

// ---------------- h1 = pz @ Wc + bc ----------------

__global__ __launch_bounds__(256) void k_gemm1(const float* __restrict__ pz, const float* __restrict__ Wc,
                                               const float* __restrict__ bc, float* __restrict__ h1, int N) {
  const int lane = threadIdx.x & 63;
  float w0[64], w1[64];
#pragma unroll
  for (int d = 0; d < 64; ++d) {
    w0[d] = Wc[d * 128 + lane];
    w1[d] = Wc[d * 128 + 64 + lane];
  }
  const float b0 = bc[lane], b1v = bc[64 + lane];
  const int nw = (gridDim.x * blockDim.x) >> 6;
  const int w_id = RFL((blockIdx.x * blockDim.x + threadIdx.x) >> 6);
  for (int r = w_id; r < N; r += nw) {
    const float* __restrict__ xr = pz + (size_t)r * 64;
    float a0 = 0.f, a1 = 0.f, a2 = 0.f, a3 = 0.f;
#pragma unroll
    for (int d = 0; d < 64; d += 2) {
      a0 += xr[d] * w0[d];
      a1 += xr[d] * w1[d];
      a2 += xr[d + 1] * w0[d + 1];
      a3 += xr[d + 1] * w1[d + 1];
    }
    size_t o = (size_t)r * 128 + lane;
    h1[o] = b0 + a0 + a2;
    h1[o + 64] = b1v + a1 + a3;
  }
}

// ---------------- gather layer 1: x1[d] = h1[d]*dinv^2 + sum_in h1[s]*nrm ----------------
// one wave per dst node; lane = feature (2 per lane); 4-edge unroll.

__global__ __launch_bounds__(256) void k_gather1(const int* __restrict__ row, const int* __restrict__ cnt,
                                                 const int* __restrict__ esrc, const float* __restrict__ enrm,
                                                 const float* __restrict__ h1, const float* __restrict__ dinv,
                                                 float* __restrict__ x1, int N) {
  const int lane = threadIdx.x & 63;
  const int node = RFL(blockIdx.x * 4 + (threadIdx.x >> 6));
  if (node >= N) return;
  const int rs = RFL(row[node]);
  const int ne = RFL(cnt[node]);
  const float di = dinv[node];
  float a0 = h1[(size_t)node * 128 + lane] * di * di;
  float a1 = h1[(size_t)node * 128 + 64 + lane] * di * di;
  int j = 0;
  for (; j + 4 <= ne; j += 4) {
    int s0 = esrc[rs + j], s1 = esrc[rs + j + 1], s2 = esrc[rs + j + 2], s3 = esrc[rs + j + 3];
    float w0 = enrm[rs + j], w1 = enrm[rs + j + 1], w2 = enrm[rs + j + 2], w3 = enrm[rs + j + 3];
    const float* p0 = h1 + (size_t)s0 * 128;
    const float* p1 = h1 + (size_t)s1 * 128;
    const float* p2 = h1 + (size_t)s2 * 128;
    const float* p3 = h1 + (size_t)s3 * 128;
    a0 += p0[lane] * w0;      a1 += p0[64 + lane] * w0;
    a0 += p1[lane] * w1;      a1 += p1[64 + lane] * w1;
    a0 += p2[lane] * w2;      a1 += p2[64 + lane] * w2;
    a0 += p3[lane] * w3;      a1 += p3[64 + lane] * w3;
  }
  for (; j < ne; ++j) {
    int s = esrc[rs + j];
    float w = enrm[rs + j];
    a0 += h1[(size_t)s * 128 + lane] * w;
    a1 += h1[(size_t)s * 128 + 64 + lane] * w;
  }
  x1[(size_t)node * 128 + lane] = a0;
  x1[(size_t)node * 128 + 64 + lane] = a1;
}

// ---------------- h2 = relu(x1 + b1) @ W2 ----------------

__global__ __launch_bounds__(256) void k_gemm2(const float* __restrict__ x1, const float* __restrict__ b1,
                                               const float* __restrict__ W2, float* __restrict__ h2, int N) {
  const int lane = threadIdx.x & 63;
  const int col = lane & 31;
  float w[128];
#pragma unroll
  for (int d = 0; d < 128; ++d) w[d] = W2[d * 32 + col];
  const int nw = (gridDim.x * blockDim.x) >> 6;
  const int w_id = RFL((blockIdx.x * blockDim.x + threadIdx.x) >> 6);
  for (int r = w_id; r < N; r += nw) {
    const float* __restrict__ xr = x1 + (size_t)r * 128;
    float a0 = 0.f, a1 = 0.f, a2 = 0.f, a3 = 0.f;
#pragma unroll
    for (int d = 0; d < 128; d += 4) {
      a0 += fmaxf(xr[d + 0] + b1[d + 0], 0.f) * w[d + 0];
      a1 += fmaxf(xr[d + 1] + b1[d + 1], 0.f) * w[d + 1];
      a2 += fmaxf(xr[d + 2] + b1[d + 2], 0.f) * w[d + 2];
      a3 += fmaxf(xr[d + 3] + b1[d + 3], 0.f) * w[d + 3];
    }
    if (lane < 32) h2[(size_t)r * 32 + col] = (a0 + a1) + (a2 + a3);
  }
}

// ---------------- gather layer 2: x2[d] = h2[d]*dinv^2 + sum_in h2[s]*nrm (32 feats) ----------------
// one wave per dst node; 2 edges in flight (half = lane>>5), 2-deep unroll per half.

__global__ __launch_bounds__(256) void k_gather2(const int* __restrict__ row, const int* __restrict__ cnt,
                                                 const int* __restrict__ esrc, const float* __restrict__ enrm,
                                                 const float* __restrict__ h2, const float* __restrict__ dinv,
                                                 float* __restrict__ x2, int N) {
  const int lane = threadIdx.x & 63;
  const int node = RFL(blockIdx.x * 4 + (threadIdx.x >> 6));
  if (node >= N) return;
  const int half = lane >> 5, f = lane & 31;
  const int rs = RFL(row[node]);
  const int ne = RFL(cnt[node]);
  const float di = dinv[node];
  float a = 0.f, b = 0.f;
  if (half == 0) a = h2[(size_t)node * 32 + f] * di * di;
  int j = half;
  for (; j + 2 < ne; j += 4) {
    int s0 = esrc[rs + j], s1 = esrc[rs + j + 2];
    float w0 = enrm[rs + j], w1 = enrm[rs + j + 2];
    a += h2[(size_t)s0 * 32 + f] * w0;
    b += h2[(size_t)s1 * 32 + f] * w1;
  }
  for (; j < ne; j += 2) {
    int s = esrc[rs + j];
    float w = enrm[rs + j];
    a += h2[(size_t)s * 32 + f] * w;
  }
  a += b;
  a += __shfl_xor(a, 32, 64);
  if (half == 0) x2[(size_t)node * 32 + f] = a;
}

// ---------------- query MLP ----------------

__global__ __launch_bounds__(256) void k_mlp(const int* __restrict__ qidx, const float* __restrict__ x2,
                                             const float* __restrict__ b2, const float* __restrict__ Wm1,
                                             const float* __restrict__ bm1, const float* __restrict__ Wm2,
                                             const float* __restrict__ bm2, float* __restrict__ out, int B) {
  int t = blockIdx.x * 256 + threadIdx.x;
  if (t >= B) return;
  int n = qidx[t];
  float qv[32];
#pragma unroll
  for (int k = 0; k < 32; ++k) qv[k] = fmaxf(x2[(size_t)n * 32 + k] + b2[k], 0.f);
  float acc = bm2[0];
  for (int j = 0; j < 64; ++j) {
    float h = bm1[j];
#pragma unroll
    for (int k = 0; k < 32; ++k) h += qv[k] * Wm1[k * 64 + j];
    acc += fmaxf(h, 0.f) * Wm2[j];
  }
  out[t] = acc;
}

// ---------------- launcher ----------------

extern "C" void kernel_launch(void* const* d_in, const int* in_sizes, int n_in,
                              void* d_out, int out_size, void* d_ws, size_t ws_size,
                              hipStream_t stream) {
  const float* X    = (const float*)d_in[0];
  const int*   mask = (const int*)d_in[1];
  const int*   ei   = (const int*)d_in[2];
  const int*   qidx = (const int*)d_in[3];
  const float* WE   = (const float*)d_in[4];
  const float* bE   = (const float*)d_in[5];
  const float* WA   = (const float*)d_in[6];
  const float* bA   = (const float*)d_in[7];
  const float* Wout = (const float*)d_in[8];
  const float* bout = (const float*)d_in[9];
  const float* W1   = (const float*)d_in[10];
  const float* b1   = (const float*)d_in[11];
  const float* W2   = (const float*)d_in[12];
  const float* b2   = (const float*)d_in[13];
  const float* Wm1  = (const float*)d_in[14];
  const float* bm1  = (const float*)d_in[15];
  const float* Wm2  = (const float*)d_in[16];
  const float* bm2  = (const float*)d_in[17];

  const int N = in_sizes[1] / 20;
  const int E = in_sizes[2] / 2;
  const int B = in_sizes[3];
  const int* src  = ei;
  const int* dstp = ei + E;

  const size_t Na = ((size_t)N + 63) & ~(size_t)63;
  const size_t Ea = ((size_t)E + 63) & ~(size_t)63;
  const int P = (N + 255) / 256;
  const size_t Pa = ((size_t)P + 63) & ~(size_t)63;

  float* ws      = (float*)d_ws;
  float* dinv    = ws;                       // N
  int*   cnt     = (int*)(dinv + Na);        // N
  int*   rowp    = cnt + Na;                 // N
  int*   cursor  = rowp + Na;                // N
  int*   partial = cursor + Na;              // P
  int*   esrc    = partial + Pa;             // E
  float* enrm    = (float*)(esrc + Ea);      // E
  float* Wc      = enrm + Ea;                // 8192
  float* bc      = Wc + 8192;                // 128
  float* pz      = bc + 128;                 // N*64
  float* h1      = pz + (size_t)N * 64;      // N*128
  float* x1      = h1 + (size_t)N * 128;     // N*128
  float* h2      = pz;                       // reuse pz (dead after gemm1): N*32
  float* x2      = pz + (size_t)N * 32;      // N*32

  const int nb = (N + 255) / 256;
  const int nw4 = (N + 3) / 4;

  k_zero<<<nb, 256, 0, stream>>>(cnt, N);
  k_count<<<1024, 256, 0, stream>>>(dstp, cnt, E);
  k_dinv<<<nb, 256, 0, stream>>>(cnt, dinv, N);
  k_scan1<<<P, 256, 0, stream>>>(cnt, rowp, partial, N);
  k_scan2<<<1, 256, 0, stream>>>(partial, P);
  k_scan3<<<P, 256, 0, stream>>>(rowp, partial, cursor, N);
  k_edge_fill<<<1024, 256, 0, stream>>>(src, dstp, dinv, cursor, esrc, enrm, E);
  k_wc<<<33, 256, 0, stream>>>(Wout, bout, W1, Wc, bc);
  k_pool<<<nw4, 256, 0, stream>>>(X, mask, WE, bE, WA, bA, pz, N);
  k_gemm1<<<1024, 256, 0, stream>>>(pz, Wc, bc, h1, N);
  k_gather1<<<nw4, 256, 0, stream>>>(rowp, cnt, esrc, enrm, h1, dinv, x1, N);
  k_gemm2<<<1024, 256, 0, stream>>>(x1, b1, W2, h2, N);
  k_gather2<<<nw4, 256, 0, stream>>>(rowp, cnt, esrc, enrm, h2, dinv, x2, N);
  k_mlp<<<(B + 255) / 256, 256, 0, stream>>>(qidx, x2, b2, Wm1, bm1, Wm2, bm2, (float*)d_out, B);
}

// Round 3
// 929.698 us; speedup vs baseline: 5.5146x; 1.5523x over previous
//
#include <hip/hip_runtime.h>
#include <math.h>

#define RFL(x) __builtin_amdgcn_readfirstlane(x)
#define RL(x, l) __int_as_float(__builtin_amdgcn_readlane(__float_as_int(x), (l)))

// ---------------- degree histogram (int) ----------------

__global__ __launch_bounds__(256) void k_zero(int* p, int n) {
  int t = blockIdx.x * 256 + threadIdx.x;
  if (t < n) p[t] = 0;
}

__global__ __launch_bounds__(256) void k_count(const int* __restrict__ dst, int* cnt, int E) {
  int stride = gridDim.x * blockDim.x;
  for (int e = blockIdx.x * blockDim.x + threadIdx.x; e < E; e += stride)
    atomicAdd(&cnt[dst[e]], 1);
}

__global__ __launch_bounds__(256) void k_dinv(const int* __restrict__ cnt, float* dinv, int N) {
  int t = blockIdx.x * 256 + threadIdx.x;
  if (t < N) dinv[t] = rsqrtf((float)cnt[t] + 1.0f);  // +1 self-loop
}

// ---------------- exclusive scan: cnt -> row_start ----------------

__global__ __launch_bounds__(256) void k_scan1(const int* __restrict__ cnt, int* __restrict__ row,
                                               int* __restrict__ partial, int N) {
  __shared__ int sm[256];
  int t = threadIdx.x, g = blockIdx.x * 256 + t;
  int v = (g < N) ? cnt[g] : 0;
  sm[t] = v;
  __syncthreads();
#pragma unroll
  for (int off = 1; off < 256; off <<= 1) {
    int x = 0;
    if (t >= off) x = sm[t - off];
    __syncthreads();
    if (t >= off) sm[t] += x;
    __syncthreads();
  }
  if (g < N) row[g] = sm[t] - v;  // exclusive within block
  if (t == 255) partial[blockIdx.x] = sm[255];
}

__global__ __launch_bounds__(256) void k_scan2(int* __restrict__ partial, int P) {
  __shared__ int sm[256];
  int t = threadIdx.x;
  int carry = 0;
  for (int base = 0; base < P; base += 256) {
    int idx = base + t;
    int v = (idx < P) ? partial[idx] : 0;
    sm[t] = v;
    __syncthreads();
#pragma unroll
    for (int off = 1; off < 256; off <<= 1) {
      int x = 0;
      if (t >= off) x = sm[t - off];
      __syncthreads();
      if (t >= off) sm[t] += x;
      __syncthreads();
    }
    if (idx < P) partial[idx] = carry + sm[t] - v;  // exclusive
    int tot = sm[255];
    __syncthreads();
    carry += tot;
  }
}

__global__ __launch_bounds__(256) void k_scan3(int* __restrict__ row, const int* __restrict__ partial,
                                               int* __restrict__ cursor, int N) {
  int g = blockIdx.x * 256 + threadIdx.x;
  if (g < N) {
    int v = row[g] + partial[blockIdx.x];
    row[g] = v;
    cursor[g] = v;
  }
}

// ---------------- edge placement: dst-sorted src ----------------

__global__ __launch_bounds__(256) void k_edge_fill(const int* __restrict__ src, const int* __restrict__ dst,
                                                   int* __restrict__ cursor, int* __restrict__ esrc, int E) {
  int stride = gridDim.x * blockDim.x;
  for (int e = blockIdx.x * blockDim.x + threadIdx.x; e < E; e += stride) {
    int s = src[e], d = dst[e];
    int pos = atomicAdd(&cursor[d], 1);
    esrc[pos] = s;
  }
}

// ---------------- W_c = W_out @ W1, b_c = b_out @ W1 ----------------

__global__ __launch_bounds__(256) void k_wc(const float* __restrict__ Wout, const float* __restrict__ bout,
                                            const float* __restrict__ W1, float* __restrict__ Wc,
                                            float* __restrict__ bc) {
  int t = blockIdx.x * 256 + threadIdx.x;
  if (t >= 65 * 128) return;
  int h = t >> 7, o = t & 127;
  const float* row = (h < 64) ? (Wout + h * 128) : bout;
  float a = 0.f;
  for (int d = 0; d < 128; ++d) a += row[d] * W1[d * 128 + o];
  if (h < 64) Wc[h * 128 + o] = a;
  else bc[o] = a;
}

// ---------------- attention pooling ----------------
// one wave per node; lane = h holds WE[:,h] in 128 VGPRs; X rows loaded
// coalesced (float2/lane) and broadcast via v_readlane (const lane index).
// online softmax (running max m, denom Zs, weighted sum P).

__global__ __launch_bounds__(256, 2) void k_pool(const float* __restrict__ X, const int* __restrict__ mask,
                                                 const float* __restrict__ WE, const float* __restrict__ bE,
                                                 const float* __restrict__ WA, const float* __restrict__ bA,
                                                 float* __restrict__ pz, int N) {
  const int lane = threadIdx.x & 63;
  const int node = blockIdx.x * 4 + (threadIdx.x >> 6);
  if (node >= N) return;

  float w[128];
#pragma unroll
  for (int d = 0; d < 128; ++d) w[d] = WE[d * 64 + lane];
  const float be = bE[lane];
  const float wa = WA[lane];
  const float ba = bA[0];

  const float* __restrict__ xb = X + (size_t)node * 2560 + 2 * lane;  // lane's float2 slot
  const int* __restrict__ mr = mask + node * 20;

  float2 xc = *(const float2*)xb;  // row 0
  float m = -INFINITY, Zs = 0.f, P = 0.f;
#pragma unroll 2
  for (int s = 0; s < 20; ++s) {
    float2 xn = xc;
    if (s < 19) xn = *(const float2*)(xb + (size_t)(s + 1) * 128);  // prefetch next row
    const int xi = __float_as_int(xc.x), yi = __float_as_int(xc.y);
    float p0 = 0.f, p1 = 0.f, p2 = 0.f, p3 = 0.f;
#pragma unroll
    for (int d0 = 0; d0 < 64; d0 += 2) {
      float a0 = RL((float&)xi, d0);      // X[s, 2*d0]
      float b0 = RL((float&)yi, d0);      // X[s, 2*d0+1]
      float a1 = RL((float&)xi, d0 + 1);  // X[s, 2*d0+2]
      float b1 = RL((float&)yi, d0 + 1);  // X[s, 2*d0+3]
      p0 += a0 * w[2 * d0 + 0];
      p1 += b0 * w[2 * d0 + 1];
      p2 += a1 * w[2 * d0 + 2];
      p3 += b1 * w[2 * d0 + 3];
    }
    float z = fmaxf(be + ((p0 + p1) + (p2 + p3)), 0.f);  // z[s, lane]
    float sc = z * wa;
#pragma unroll
    for (int off = 32; off > 0; off >>= 1) sc += __shfl_xor(sc, off, 64);
    sc += ba;  // score[s], uniform
    if (mr[s] != 0) {
      if (sc > m) {
        float scale = __expf(m - sc);  // first iter: exp(-inf)=0
        Zs = Zs * scale + 1.f;
        P = P * scale + z;
        m = sc;
      } else {
        float p = __expf(sc - m);
        Zs += p;
        P += p * z;
      }
    }
    xc = xn;
  }
  pz[(size_t)node * 64 + lane] = P / Zs;
}

// ---------------- h1p = (pz @ Wc + bc) * dinv[r] ----------------
// wave per row; lane holds Wc[:,lane], Wc[:,lane+64]; pz row broadcast via readlane.

__global__ __launch_bounds__(256, 2) void k_gemm1(const float* __restrict__ pz, const float* __restrict__ Wc,
                                                  const float* __restrict__ bc, const float* __restrict__ dinv,
                                                  float* __restrict__ h1p, int N) {
  const int lane = threadIdx.x & 63;
  float w0[64], w1[64];
#pragma unroll
  for (int d = 0; d < 64; ++d) {
    w0[d] = Wc[d * 128 + lane];
    w1[d] = Wc[d * 128 + 64 + lane];
  }
  const float b0 = bc[lane], b1v = bc[64 + lane];
  const int nw = (gridDim.x * blockDim.x) >> 6;
  const int w_id = (blockIdx.x * blockDim.x + threadIdx.x) >> 6;
  for (int r = w_id; r < N; r += nw) {
    const float xv = pz[(size_t)r * 64 + lane];
    const int xi = __float_as_int(xv);
    float p0 = 0.f, p1 = 0.f, p2 = 0.f, p3 = 0.f;
#pragma unroll
    for (int d0 = 0; d0 < 64; d0 += 2) {
      float a0 = RL((float&)xi, d0);
      float a1 = RL((float&)xi, d0 + 1);
      p0 += a0 * w0[d0];
      p1 += a0 * w1[d0];
      p2 += a1 * w0[d0 + 1];
      p3 += a1 * w1[d0 + 1];
    }
    float di = dinv[r];
    size_t o = (size_t)r * 128 + lane;
    h1p[o] = (b0 + p0 + p2) * di;
    h1p[o + 64] = (b1v + p1 + p3) * di;
  }
}

// ---------------- gather layer 1: x1[d] = dinv[d]*(sum_in h1p[s] + h1p[d]*dinv[d]) ----------------
// one wave per dst node; lane = float2 feature slot; 4-edge unroll; no per-edge weights.

__global__ __launch_bounds__(256) void k_gather1(const int* __restrict__ row, const int* __restrict__ cnt,
                                                 const int* __restrict__ esrc, const float* __restrict__ h1p,
                                                 const float* __restrict__ dinv, float* __restrict__ x1, int N) {
  const int lane = threadIdx.x & 63;
  const int node = RFL(blockIdx.x * 4 + (threadIdx.x >> 6));
  if (node >= N) return;
  const int rs = RFL(row[node]);
  const int ne = RFL(cnt[node]);
  const float di = dinv[node];
  const float2* __restrict__ h2v = (const float2*)h1p;
  float2 sv = h2v[(size_t)node * 64 + lane];
  float a0 = sv.x * di, a1 = sv.y * di;
  int j = 0;
  for (; j + 4 <= ne; j += 4) {
    int s0 = esrc[rs + j], s1 = esrc[rs + j + 1], s2 = esrc[rs + j + 2], s3 = esrc[rs + j + 3];
    float2 v0 = h2v[(size_t)s0 * 64 + lane];
    float2 v1 = h2v[(size_t)s1 * 64 + lane];
    float2 v2 = h2v[(size_t)s2 * 64 + lane];
    float2 v3 = h2v[(size_t)s3 * 64 + lane];
    a0 += v0.x; a1 += v0.y;
    a0 += v1.x; a1 += v1.y;
    a0 += v2.x; a1 += v2.y;
    a0 += v3.x; a1 += v3.y;
  }
  for (; j < ne; ++j) {
    int s = esrc[rs + j];
    float2 v = h2v[(size_t)s * 64 + lane];
    a0 += v.x; a1 += v.y;
  }
  ((float2*)x1)[(size_t)node * 64 + lane] = make_float2(a0 * di, a1 * di);
}

// ---------------- h2p = (relu(x1 + b1) @ W2) * dinv[r] ----------------
// wave per row; lane holds W2[:, lane&31]; x row broadcast via readlane (cols duplicated).

__global__ __launch_bounds__(256, 2) void k_gemm2(const float* __restrict__ x1, const float* __restrict__ b1,
                                                  const float* __restrict__ W2, const float* __restrict__ dinv,
                                                  float* __restrict__ h2p, int N) {
  const int lane = threadIdx.x & 63;
  const int col = lane & 31;
  float w[128];
#pragma unroll
  for (int d = 0; d < 128; ++d) w[d] = W2[d * 32 + col];
  const float bb0 = b1[lane], bb1 = b1[64 + lane];
  const int nw = (gridDim.x * blockDim.x) >> 6;
  const int w_id = (blockIdx.x * blockDim.x + threadIdx.x) >> 6;
  for (int r = w_id; r < N; r += nw) {
    float rx0 = fmaxf(x1[(size_t)r * 128 + lane] + bb0, 0.f);
    float rx1 = fmaxf(x1[(size_t)r * 128 + 64 + lane] + bb1, 0.f);
    const int xi0 = __float_as_int(rx0), xi1 = __float_as_int(rx1);
    float p0 = 0.f, p1 = 0.f, p2 = 0.f, p3 = 0.f;
#pragma unroll
    for (int d0 = 0; d0 < 64; d0 += 2) {
      float a0 = RL((float&)xi0, d0);
      float a1 = RL((float&)xi0, d0 + 1);
      float c0 = RL((float&)xi1, d0);
      float c1 = RL((float&)xi1, d0 + 1);
      p0 += a0 * w[d0];
      p1 += a1 * w[d0 + 1];
      p2 += c0 * w[64 + d0];
      p3 += c1 * w[64 + d0 + 1];
    }
    if (lane < 32) {
      float di = dinv[r];
      h2p[(size_t)r * 32 + col] = ((p0 + p1) + (p2 + p3)) * di;
    }
  }
}

// ---------------- gather layer 2: x2[d] = dinv[d]*(sum_in h2p[s] + h2p[d]*dinv[d]) ----------------
// one wave per dst node; 4 edge-quarters in flight; float2 per lane over 32 feats.

__global__ __launch_bounds__(256) void k_gather2(const int* __restrict__ row, const int* __restrict__ cnt,
                                                 const int* __restrict__ esrc, const float* __restrict__ h2p,
                                                 const float* __restrict__ dinv, float* __restrict__ x2, int N) {
  const int lane = threadIdx.x & 63;
  const int node = RFL(blockIdx.x * 4 + (threadIdx.x >> 6));
  if (node >= N) return;
  const int q = lane >> 4, f2 = lane & 15;
  const int rs = RFL(row[node]);
  const int ne = RFL(cnt[node]);
  const float di = dinv[node];
  const float2* __restrict__ hv = (const float2*)h2p;
  float a0 = 0.f, a1 = 0.f;
  if (q == 0) {
    float2 sv = hv[(size_t)node * 16 + f2];
    a0 = sv.x * di;
    a1 = sv.y * di;
  }
  int j = q;
  for (; j + 4 < ne; j += 8) {
    int s0 = esrc[rs + j], s1 = esrc[rs + j + 4];
    float2 v0 = hv[(size_t)s0 * 16 + f2];
    float2 v1 = hv[(size_t)s1 * 16 + f2];
    a0 += v0.x + v1.x;
    a1 += v0.y + v1.y;
  }
  for (; j < ne; j += 4) {
    int s = esrc[rs + j];
    float2 v = hv[(size_t)s * 16 + f2];
    a0 += v.x;
    a1 += v.y;
  }
  a0 += __shfl_xor(a0, 16, 64);
  a0 += __shfl_xor(a0, 32, 64);
  a1 += __shfl_xor(a1, 16, 64);
  a1 += __shfl_xor(a1, 32, 64);
  if (q == 0) ((float2*)x2)[(size_t)node * 16 + f2] = make_float2(a0 * di, a1 * di);
}

// ---------------- query MLP ----------------

__global__ __launch_bounds__(256) void k_mlp(const int* __restrict__ qidx, const float* __restrict__ x2,
                                             const float* __restrict__ b2, const float* __restrict__ Wm1,
                                             const float* __restrict__ bm1, const float* __restrict__ Wm2,
                                             const float* __restrict__ bm2, float* __restrict__ out, int B) {
  int t = blockIdx.x * 256 + threadIdx.x;
  if (t >= B) return;
  int n = qidx[t];
  float qv[32];
#pragma unroll
  for (int k = 0; k < 32; ++k) qv[k] = fmaxf(x2[(size_t)n * 32 + k] + b2[k], 0.f);
  float acc = bm2[0];
  for (int j = 0; j < 64; ++j) {
    float h = bm1[j];
#pragma unroll
    for (int k = 0; k < 32; ++k) h += qv[k] * Wm1[k * 64 + j];
    acc += fmaxf(h, 0.f) * Wm2[j];
  }
  out[t] = acc;
}

// ---------------- launcher ----------------

extern "C" void kernel_launch(void* const* d_in, const int* in_sizes, int n_in,
                              void* d_out, int out_size, void* d_ws, size_t ws_size,
                              hipStream_t stream) {
  const float* X    = (const float*)d_in[0];
  const int*   mask = (const int*)d_in[1];
  const int*   ei   = (const int*)d_in[2];
  const int*   qidx = (const int*)d_in[3];
  const float* WE   = (const float*)d_in[4];
  const float* bE   = (const float*)d_in[5];
  const float* WA   = (const float*)d_in[6];
  const float* bA   = (const float*)d_in[7];
  const float* Wout = (const float*)d_in[8];
  const float* bout = (const float*)d_in[9];
  const float* W1   = (const float*)d_in[10];
  const float* b1   = (const float*)d_in[11];
  const float* W2   = (const float*)d_in[12];
  const float* b2   = (const float*)d_in[13];
  const float* Wm1  = (const float*)d_in[14];
  const float* bm1  = (const float*)d_in[15];
  const float* Wm2  = (const float*)d_in[16];
  const float* bm2  = (const float*)d_in[17];

  const int N = in_sizes[1] / 20;
  const int E = in_sizes[2] / 2;
  const int B = in_sizes[3];
  const int* src  = ei;
  const int* dstp = ei + E;

  const size_t Na = ((size_t)N + 63) & ~(size_t)63;
  const size_t Ea = ((size_t)E + 63) & ~(size_t)63;
  const int P = (N + 255) / 256;
  const size_t Pa = ((size_t)P + 63) & ~(size_t)63;

  float* ws      = (float*)d_ws;
  float* dinv    = ws;                       // N
  int*   cnt     = (int*)(dinv + Na);        // N
  int*   rowp    = cnt + Na;                 // N
  int*   cursor  = rowp + Na;                // N
  int*   partial = cursor + Na;              // P
  int*   esrc    = partial + Pa;             // E
  float* Wc      = (float*)(esrc + Ea);      // 8192
  float* bc      = Wc + 8192;                // 128
  float* pz      = bc + 128;                 // N*64
  float* h1p     = pz + (size_t)N * 64;      // N*128
  float* x1      = h1p + (size_t)N * 128;    // N*128
  float* h2p     = pz;                       // reuse pz (dead after gemm1): N*32
  float* x2      = pz + (size_t)N * 32;      // N*32

  const int nb = (N + 255) / 256;
  const int nw4 = (N + 3) / 4;

  k_zero<<<nb, 256, 0, stream>>>(cnt, N);
  k_count<<<1024, 256, 0, stream>>>(dstp, cnt, E);
  k_dinv<<<nb, 256, 0, stream>>>(cnt, dinv, N);
  k_scan1<<<P, 256, 0, stream>>>(cnt, rowp, partial, N);
  k_scan2<<<1, 256, 0, stream>>>(partial, P);
  k_scan3<<<P, 256, 0, stream>>>(rowp, partial, cursor, N);
  k_edge_fill<<<1024, 256, 0, stream>>>(src, dstp, cursor, esrc, E);
  k_wc<<<33, 256, 0, stream>>>(Wout, bout, W1, Wc, bc);
  k_pool<<<nw4, 256, 0, stream>>>(X, mask, WE, bE, WA, bA, pz, N);
  k_gemm1<<<1024, 256, 0, stream>>>(pz, Wc, bc, dinv, h1p, N);
  k_gather1<<<nw4, 256, 0, stream>>>(rowp, cnt, esrc, h1p, dinv, x1, N);
  k_gemm2<<<1024, 256, 0, stream>>>(x1, b1, W2, dinv, h2p, N);
  k_gather2<<<nw4, 256, 0, stream>>>(rowp, cnt, esrc, h2p, dinv, x2, N);
  k_mlp<<<(B + 255) / 256, 256, 0, stream>>>(qidx, x2, b2, Wm1, bm1, Wm2, bm2, (float*)d_out, B);
}

// Round 6
// 667.373 us; speedup vs baseline: 7.6822x; 1.3931x over previous
//
#include <hip/hip_runtime.h>
#include <math.h>

#define RFL(x) __builtin_amdgcn_readfirstlane(x)
#define RL(x, l) __int_as_float(__builtin_amdgcn_readlane(__float_as_int(x), (l)))

// ---------------- degree histogram (int) ----------------

__global__ __launch_bounds__(256) void k_zero(int* p, int n) {
  int t = blockIdx.x * 256 + threadIdx.x;
  if (t < n) p[t] = 0;
}

__global__ __launch_bounds__(256) void k_count(const int* __restrict__ dst, int* cnt, int E) {
  int stride = gridDim.x * blockDim.x;
  for (int e = blockIdx.x * blockDim.x + threadIdx.x; e < E; e += stride)
    atomicAdd(&cnt[dst[e]], 1);
}

__global__ __launch_bounds__(256) void k_dinv(const int* __restrict__ cnt, float* dinv, int N) {
  int t = blockIdx.x * 256 + threadIdx.x;
  if (t < N) dinv[t] = rsqrtf((float)cnt[t] + 1.0f);  // +1 self-loop
}

// ---------------- exclusive scan: cnt -> row_start ----------------

__global__ __launch_bounds__(256) void k_scan1(const int* __restrict__ cnt, int* __restrict__ row,
                                               int* __restrict__ partial, int N) {
  __shared__ int sm[256];
  int t = threadIdx.x, g = blockIdx.x * 256 + t;
  int v = (g < N) ? cnt[g] : 0;
  sm[t] = v;
  __syncthreads();
#pragma unroll
  for (int off = 1; off < 256; off <<= 1) {
    int x = 0;
    if (t >= off) x = sm[t - off];
    __syncthreads();
    if (t >= off) sm[t] += x;
    __syncthreads();
  }
  if (g < N) row[g] = sm[t] - v;  // exclusive within block
  if (t == 255) partial[blockIdx.x] = sm[255];
}

__global__ __launch_bounds__(256) void k_scan2(int* __restrict__ partial, int P) {
  __shared__ int sm[256];
  int t = threadIdx.x;
  int carry = 0;
  for (int base = 0; base < P; base += 256) {
    int idx = base + t;
    int v = (idx < P) ? partial[idx] : 0;
    sm[t] = v;
    __syncthreads();
#pragma unroll
    for (int off = 1; off < 256; off <<= 1) {
      int x = 0;
      if (t >= off) x = sm[t - off];
      __syncthreads();
      if (t >= off) sm[t] += x;
      __syncthreads();
    }
    if (idx < P) partial[idx] = carry + sm[t] - v;  // exclusive
    int tot = sm[255];
    __syncthreads();
    carry += tot;
  }
}

__global__ __launch_bounds__(256) void k_scan3(int* __restrict__ row, const int* __restrict__ partial,
                                               int* __restrict__ cursor, int N) {
  int g = blockIdx.x * 256 + threadIdx.x;
  if (g < N) {
    int v = row[g] + partial[blockIdx.x];
    row[g] = v;
    cursor[g] = v;
  }
}

// ---------------- edge placement: dst-sorted src ----------------

__global__ __launch_bounds__(256) void k_edge_fill(const int* __restrict__ src, const int* __restrict__ dst,
                                                   int* __restrict__ cursor, int* __restrict__ esrc, int E) {
  int stride = gridDim.x * blockDim.x;
  for (int e = blockIdx.x * blockDim.x + threadIdx.x; e < E; e += stride) {
    int s = src[e], d = dst[e];
    int pos = atomicAdd(&cursor[d], 1);
    esrc[pos] = s;
  }
}

// ---------------- W_c = W_out @ W1, b_c = b_out @ W1 ----------------

__global__ __launch_bounds__(256) void k_wc(const float* __restrict__ Wout, const float* __restrict__ bout,
                                            const float* __restrict__ W1, float* __restrict__ Wc,
                                            float* __restrict__ bc) {
  int t = blockIdx.x * 256 + threadIdx.x;
  if (t >= 65 * 128) return;
  int h = t >> 7, o = t & 127;
  const float* row = (h < 64) ? (Wout + h * 128) : bout;
  float a = 0.f;
  for (int d = 0; d < 128; ++d) a += row[d] * W1[d * 128 + o];
  if (h < 64) Wc[h * 128 + o] = a;
  else bc[o] = a;
}

// ---------------- attention pooling (X-stationary) ----------------
// Wave owns 60 consecutive set-rows = 3 nodes (lane = row; lanes 60-63 idle).
// Lane accumulates its row's z[64] in VGPRs; WE broadcast via wave-uniform
// loads (scalar pipe) -> inner loop is pure v_fmac.
// FIX vs R4/R5: K-loop now covers ALL 128 input dims (16 chunks of 8),
// previously only 64 (8 chunks) -> deterministic 4.4e-3 absmax failure.

__global__ __launch_bounds__(256, 3) void k_pool(const float* __restrict__ X, const int* __restrict__ mask,
                                                 const float* __restrict__ WE, const float* __restrict__ bE,
                                                 const float* __restrict__ WA, const float* __restrict__ bA,
                                                 float* __restrict__ pz, int N) {
  __shared__ float lds_s[4][64];
  __shared__ float lds_z[4][64 * 20];
  const int lane = threadIdx.x & 63;
  const int wid = threadIdx.x >> 6;

  const long long totRows = (long long)N * 20;
  long long row = (long long)blockIdx.x * 240 + wid * 60 + lane;
  const float* __restrict__ xr = X + (row < totRows ? row : (totRows - 1)) * 128;

  float acc[64];
#pragma unroll
  for (int h = 0; h < 64; ++h) acc[h] = 0.f;

  float x[8], xn[8];
  *(float4*)&x[0] = *(const float4*)(xr + 0);
  *(float4*)&x[4] = *(const float4*)(xr + 4);

#pragma unroll 2
  for (int c = 0; c < 16; ++c) {
    const int cn = (c + 1) & 15;  // wrap: chunk-15 prefetches chunk-0 again (harmless, branch-free)
    *(float4*)&xn[0] = *(const float4*)(xr + cn * 8 + 0);
    *(float4*)&xn[4] = *(const float4*)(xr + cn * 8 + 4);
    const float* __restrict__ wp = WE + c * 8 * 64;
#pragma unroll
    for (int d = 0; d < 8; ++d) {
#pragma unroll
      for (int hq = 0; hq < 16; ++hq) {
        const float4 we = *(const float4*)(wp + d * 64 + hq * 4);  // wave-uniform
        acc[hq * 4 + 0] += we.x * x[d];
        acc[hq * 4 + 1] += we.y * x[d];
        acc[hq * 4 + 2] += we.z * x[d];
        acc[hq * 4 + 3] += we.w * x[d];
      }
    }
#pragma unroll
    for (int d = 0; d < 8; ++d) x[d] = xn[d];
  }

  // z = relu(acc + bE); score = z . WA + bA
  float sc = bA[0];
#pragma unroll
  for (int h = 0; h < 64; ++h) {
    float z = fmaxf(acc[h] + bE[h], 0.f);
    acc[h] = z;
    sc = fmaf(z, WA[h], sc);
  }

  const int ln = (lane < 60) ? (lane / 20) : 0;  // node-in-wave 0..2
  const int s_in = lane - ln * 20;
  const int node = blockIdx.x * 12 + wid * 3 + ln;
  const bool act = (lane < 60) && (node < N);
  const int mk = act ? mask[node * 20 + s_in] : 0;
  const float NEG = -3.0e38f;
  if (!act || mk == 0) sc = NEG;

  float* ss = &lds_s[wid][0];
  ss[lane] = sc;
  __syncthreads();
  float mx = NEG;
#pragma unroll
  for (int i = 0; i < 20; ++i) mx = fmaxf(mx, ss[ln * 20 + i]);
  const float p = (sc == NEG) ? 0.f : __expf(sc - mx);  // masked -> exactly 0, no NaN
  __syncthreads();
  ss[lane] = p;
  __syncthreads();
  float den = 0.f;
#pragma unroll
  for (int i = 0; i < 20; ++i) den += ss[ln * 20 + i];
  const float wgt = p / fmaxf(den, 1e-37f);  // dead groups: 0/eps = 0, no NaN
#pragma unroll
  for (int h = 0; h < 64; ++h) acc[h] *= wgt;

  // pooled[n][h] = sum over the node's 20 lanes of acc[h], via 16-col chunks
  float* zz = &lds_z[wid][0];
  const int on = lane >> 4;   // output node 0..2 (lane<48)
  const int oh = lane & 15;   // output h within chunk
  for (int ch = 0; ch < 4; ++ch) {
    __syncthreads();  // previous iteration's reads done before overwrite
    if (lane < 60) {
#pragma unroll
      for (int col = 0; col < 16; ++col) zz[lane * 20 + col] = acc[ch * 16 + col];
    }
    __syncthreads();
    if (lane < 48) {
      float o = 0.f;
#pragma unroll
      for (int s2 = 0; s2 < 20; ++s2) o += zz[(on * 20 + s2) * 20 + oh];
      const int outNode = blockIdx.x * 12 + wid * 3 + on;
      if (outNode < N) pz[(size_t)outNode * 64 + ch * 16 + oh] = o;
    }
  }
}

// ---------------- h1p = (pz @ Wc + bc) * dinv[r] ----------------
// wave per row; lane holds Wc[:,lane], Wc[:,lane+64]; pz row broadcast via readlane.

__global__ __launch_bounds__(256, 2) void k_gemm1(const float* __restrict__ pz, const float* __restrict__ Wc,
                                                  const float* __restrict__ bc, const float* __restrict__ dinv,
                                                  float* __restrict__ h1p, int N) {
  const int lane = threadIdx.x & 63;
  float w0[64], w1[64];
#pragma unroll
  for (int d = 0; d < 64; ++d) {
    w0[d] = Wc[d * 128 + lane];
    w1[d] = Wc[d * 128 + 64 + lane];
  }
  const float b0 = bc[lane], b1v = bc[64 + lane];
  const int nw = (gridDim.x * blockDim.x) >> 6;
  const int w_id = (blockIdx.x * blockDim.x + threadIdx.x) >> 6;
  for (int r = w_id; r < N; r += nw) {
    const float xv = pz[(size_t)r * 64 + lane];
    const int xi = __float_as_int(xv);
    float p0 = 0.f, p1 = 0.f, p2 = 0.f, p3 = 0.f;
#pragma unroll
    for (int d0 = 0; d0 < 64; d0 += 2) {
      float a0 = RL((float&)xi, d0);
      float a1 = RL((float&)xi, d0 + 1);
      p0 += a0 * w0[d0];
      p1 += a0 * w1[d0];
      p2 += a1 * w0[d0 + 1];
      p3 += a1 * w1[d0 + 1];
    }
    float di = dinv[r];
    size_t o = (size_t)r * 128 + lane;
    h1p[o] = (b0 + p0 + p2) * di;
    h1p[o + 64] = (b1v + p1 + p3) * di;
  }
}

// ---------------- gather layer 1: x1[d] = dinv[d]*(sum_in h1p[s] + h1p[d]*dinv[d]) ----------------

__global__ __launch_bounds__(256) void k_gather1(const int* __restrict__ row, const int* __restrict__ cnt,
                                                 const int* __restrict__ esrc, const float* __restrict__ h1p,
                                                 const float* __restrict__ dinv, float* __restrict__ x1, int N) {
  const int lane = threadIdx.x & 63;
  const int node = RFL(blockIdx.x * 4 + (threadIdx.x >> 6));
  if (node >= N) return;
  const int rs = RFL(row[node]);
  const int ne = RFL(cnt[node]);
  const float di = dinv[node];
  const float2* __restrict__ h2v = (const float2*)h1p;
  float2 sv = h2v[(size_t)node * 64 + lane];
  float a0 = sv.x * di, a1 = sv.y * di;
  int j = 0;
  for (; j + 4 <= ne; j += 4) {
    int s0 = esrc[rs + j], s1 = esrc[rs + j + 1], s2 = esrc[rs + j + 2], s3 = esrc[rs + j + 3];
    float2 v0 = h2v[(size_t)s0 * 64 + lane];
    float2 v1 = h2v[(size_t)s1 * 64 + lane];
    float2 v2 = h2v[(size_t)s2 * 64 + lane];
    float2 v3 = h2v[(size_t)s3 * 64 + lane];
    a0 += v0.x; a1 += v0.y;
    a0 += v1.x; a1 += v1.y;
    a0 += v2.x; a1 += v2.y;
    a0 += v3.x; a1 += v3.y;
  }
  for (; j < ne; ++j) {
    int s = esrc[rs + j];
    float2 v = h2v[(size_t)s * 64 + lane];
    a0 += v.x; a1 += v.y;
  }
  ((float2*)x1)[(size_t)node * 64 + lane] = make_float2(a0 * di, a1 * di);
}

// ---------------- h2p = (relu(x1 + b1) @ W2) * dinv[r] ----------------

__global__ __launch_bounds__(256, 2) void k_gemm2(const float* __restrict__ x1, const float* __restrict__ b1,
                                                  const float* __restrict__ W2, const float* __restrict__ dinv,
                                                  float* __restrict__ h2p, int N) {
  const int lane = threadIdx.x & 63;
  const int col = lane & 31;
  float w[128];
#pragma unroll
  for (int d = 0; d < 128; ++d) w[d] = W2[d * 32 + col];
  const float bb0 = b1[lane], bb1 = b1[64 + lane];
  const int nw = (gridDim.x * blockDim.x) >> 6;
  const int w_id = (blockIdx.x * blockDim.x + threadIdx.x) >> 6;
  for (int r = w_id; r < N; r += nw) {
    float rx0 = fmaxf(x1[(size_t)r * 128 + lane] + bb0, 0.f);
    float rx1 = fmaxf(x1[(size_t)r * 128 + 64 + lane] + bb1, 0.f);
    const int xi0 = __float_as_int(rx0), xi1 = __float_as_int(rx1);
    float p0 = 0.f, p1 = 0.f, p2 = 0.f, p3 = 0.f;
#pragma unroll
    for (int d0 = 0; d0 < 64; d0 += 2) {
      float a0 = RL((float&)xi0, d0);
      float a1 = RL((float&)xi0, d0 + 1);
      float c0 = RL((float&)xi1, d0);
      float c1 = RL((float&)xi1, d0 + 1);
      p0 += a0 * w[d0];
      p1 += a1 * w[d0 + 1];
      p2 += c0 * w[64 + d0];
      p3 += c1 * w[64 + d0 + 1];
    }
    if (lane < 32) {
      float di = dinv[r];
      h2p[(size_t)r * 32 + col] = ((p0 + p1) + (p2 + p3)) * di;
    }
  }
}

// ---------------- gather layer 2 ----------------

__global__ __launch_bounds__(256) void k_gather2(const int* __restrict__ row, const int* __restrict__ cnt,
                                                 const int* __restrict__ esrc, const float* __restrict__ h2p,
                                                 const float* __restrict__ dinv, float* __restrict__ x2, int N) {
  const int lane = threadIdx.x & 63;
  const int node = RFL(blockIdx.x * 4 + (threadIdx.x >> 6));
  if (node >= N) return;
  const int q = lane >> 4, f2 = lane & 15;
  const int rs = RFL(row[node]);
  const int ne = RFL(cnt[node]);
  const float di = dinv[node];
  const float2* __restrict__ hv = (const float2*)h2p;
  float a0 = 0.f, a1 = 0.f;
  if (q == 0) {
    float2 sv = hv[(size_t)node * 16 + f2];
    a0 = sv.x * di;
    a1 = sv.y * di;
  }
  int j = q;
  for (; j + 4 < ne; j += 8) {
    int s0 = esrc[rs + j], s1 = esrc[rs + j + 4];
    float2 v0 = hv[(size_t)s0 * 16 + f2];
    float2 v1 = hv[(size_t)s1 * 16 + f2];
    a0 += v0.x + v1.x;
    a1 += v0.y + v1.y;
  }
  for (; j < ne; j += 4) {
    int s = esrc[rs + j];
    float2 v = hv[(size_t)s * 16 + f2];
    a0 += v.x;
    a1 += v.y;
  }
  a0 += __shfl_xor(a0, 16, 64);
  a0 += __shfl_xor(a0, 32, 64);
  a1 += __shfl_xor(a1, 16, 64);
  a1 += __shfl_xor(a1, 32, 64);
  if (q == 0) ((float2*)x2)[(size_t)node * 16 + f2] = make_float2(a0 * di, a1 * di);
}

// ---------------- query MLP ----------------

__global__ __launch_bounds__(256) void k_mlp(const int* __restrict__ qidx, const float* __restrict__ x2,
                                             const float* __restrict__ b2, const float* __restrict__ Wm1,
                                             const float* __restrict__ bm1, const float* __restrict__ Wm2,
                                             const float* __restrict__ bm2, float* __restrict__ out, int B) {
  int t = blockIdx.x * 256 + threadIdx.x;
  if (t >= B) return;
  int n = qidx[t];
  float qv[32];
#pragma unroll
  for (int k = 0; k < 32; ++k) qv[k] = fmaxf(x2[(size_t)n * 32 + k] + b2[k], 0.f);
  float acc = bm2[0];
  for (int j = 0; j < 64; ++j) {
    float h = bm1[j];
#pragma unroll
    for (int k = 0; k < 32; ++k) h += qv[k] * Wm1[k * 64 + j];
    acc += fmaxf(h, 0.f) * Wm2[j];
  }
  out[t] = acc;
}

// ---------------- launcher ----------------

extern "C" void kernel_launch(void* const* d_in, const int* in_sizes, int n_in,
                              void* d_out, int out_size, void* d_ws, size_t ws_size,
                              hipStream_t stream) {
  const float* X    = (const float*)d_in[0];
  const int*   mask = (const int*)d_in[1];
  const int*   ei   = (const int*)d_in[2];
  const int*   qidx = (const int*)d_in[3];
  const float* WE   = (const float*)d_in[4];
  const float* bE   = (const float*)d_in[5];
  const float* WA   = (const float*)d_in[6];
  const float* bA   = (const float*)d_in[7];
  const float* Wout = (const float*)d_in[8];
  const float* bout = (const float*)d_in[9];
  const float* W1   = (const float*)d_in[10];
  const float* b1   = (const float*)d_in[11];
  const float* W2   = (const float*)d_in[12];
  const float* b2   = (const float*)d_in[13];
  const float* Wm1  = (const float*)d_in[14];
  const float* bm1  = (const float*)d_in[15];
  const float* Wm2  = (const float*)d_in[16];
  const float* bm2  = (const float*)d_in[17];

  const int N = in_sizes[1] / 20;
  const int E = in_sizes[2] / 2;
  const int B = in_sizes[3];
  const int* src  = ei;
  const int* dstp = ei + E;

  const size_t Na = ((size_t)N + 63) & ~(size_t)63;
  const size_t Ea = ((size_t)E + 63) & ~(size_t)63;
  const int P = (N + 255) / 256;
  const size_t Pa = ((size_t)P + 63) & ~(size_t)63;

  float* ws      = (float*)d_ws;
  float* dinv    = ws;                       // N
  int*   cnt     = (int*)(dinv + Na);        // N
  int*   rowp    = cnt + Na;                 // N
  int*   cursor  = rowp + Na;                // N
  int*   partial = cursor + Na;              // P
  int*   esrc    = partial + Pa;             // E
  float* Wc      = (float*)(esrc + Ea);      // 8192
  float* bc      = Wc + 8192;                // 128
  float* pz      = bc + 128;                 // N*64
  float* h1p     = pz + (size_t)N * 64;      // N*128
  float* x1      = h1p + (size_t)N * 128;    // N*128
  float* h2p     = pz;                       // reuse pz (dead after gemm1): N*32
  float* x2      = pz + (size_t)N * 32;      // N*32

  const int nb = (N + 255) / 256;
  const int nw4 = (N + 3) / 4;
  const int nw12 = (N + 11) / 12;

  k_zero<<<nb, 256, 0, stream>>>(cnt, N);
  k_count<<<1024, 256, 0, stream>>>(dstp, cnt, E);
  k_dinv<<<nb, 256, 0, stream>>>(cnt, dinv, N);
  k_scan1<<<P, 256, 0, stream>>>(cnt, rowp, partial, N);
  k_scan2<<<1, 256, 0, stream>>>(partial, P);
  k_scan3<<<P, 256, 0, stream>>>(rowp, partial, cursor, N);
  k_edge_fill<<<1024, 256, 0, stream>>>(src, dstp, cursor, esrc, E);
  k_wc<<<33, 256, 0, stream>>>(Wout, bout, W1, Wc, bc);
  k_pool<<<nw12, 256, 0, stream>>>(X, mask, WE, bE, WA, bA, pz, N);
  k_gemm1<<<1024, 256, 0, stream>>>(pz, Wc, bc, dinv, h1p, N);
  k_gather1<<<nw4, 256, 0, stream>>>(rowp, cnt, esrc, h1p, dinv, x1, N);
  k_gemm2<<<1024, 256, 0, stream>>>(x1, b1, W2, dinv, h2p, N);
  k_gather2<<<nw4, 256, 0, stream>>>(rowp, cnt, esrc, h2p, dinv, x2, N);
  k_mlp<<<(B + 255) / 256, 256, 0, stream>>>(qidx, x2, b2, Wm1, bm1, Wm2, bm2, (float*)d_out, B);
}

// Round 7
// 652.614 us; speedup vs baseline: 7.8559x; 1.0226x over previous
//
#include <hip/hip_runtime.h>
#include <math.h>

#define RFL(x) __builtin_amdgcn_readfirstlane(x)
#define RL(x, l) __int_as_float(__builtin_amdgcn_readlane(__float_as_int(x), (l)))

// ---------------- degree histogram (int) ----------------

__global__ __launch_bounds__(256) void k_zero(int* p, int n) {
  int t = blockIdx.x * 256 + threadIdx.x;
  if (t < n) p[t] = 0;
}

__global__ __launch_bounds__(256) void k_count(const int* __restrict__ dst, int* cnt, int E) {
  int stride = gridDim.x * blockDim.x;
  for (int e = blockIdx.x * blockDim.x + threadIdx.x; e < E; e += stride)
    atomicAdd(&cnt[dst[e]], 1);
}

// ---------------- exclusive scan: cnt -> row_start ----------------

__global__ __launch_bounds__(256) void k_scan1(const int* __restrict__ cnt, int* __restrict__ row,
                                               int* __restrict__ partial, int N) {
  __shared__ int sm[256];
  int t = threadIdx.x, g = blockIdx.x * 256 + t;
  int v = (g < N) ? cnt[g] : 0;
  sm[t] = v;
  __syncthreads();
#pragma unroll
  for (int off = 1; off < 256; off <<= 1) {
    int x = 0;
    if (t >= off) x = sm[t - off];
    __syncthreads();
    if (t >= off) sm[t] += x;
    __syncthreads();
  }
  if (g < N) row[g] = sm[t] - v;  // exclusive within block
  if (t == 255) partial[blockIdx.x] = sm[255];
}

__global__ __launch_bounds__(256) void k_scan2(int* __restrict__ partial, int P) {
  __shared__ int sm[256];
  int t = threadIdx.x;
  int carry = 0;
  for (int base = 0; base < P; base += 256) {
    int idx = base + t;
    int v = (idx < P) ? partial[idx] : 0;
    sm[t] = v;
    __syncthreads();
#pragma unroll
    for (int off = 1; off < 256; off <<= 1) {
      int x = 0;
      if (t >= off) x = sm[t - off];
      __syncthreads();
      if (t >= off) sm[t] += x;
      __syncthreads();
    }
    if (idx < P) partial[idx] = carry + sm[t] - v;  // exclusive
    int tot = sm[255];
    __syncthreads();
    carry += tot;
  }
}

// scan3 + dinv fused (cnt is final here; dinv first consumed after this point)
__global__ __launch_bounds__(256) void k_scan3(int* __restrict__ row, const int* __restrict__ partial,
                                               int* __restrict__ cursor, const int* __restrict__ cnt,
                                               float* __restrict__ dinv, int N) {
  int g = blockIdx.x * 256 + threadIdx.x;
  if (g < N) {
    int v = row[g] + partial[blockIdx.x];
    row[g] = v;
    cursor[g] = v;
    dinv[g] = rsqrtf((float)cnt[g] + 1.0f);  // +1 self-loop
  }
}

// ---------------- edge placement: dst-sorted src ----------------

__global__ __launch_bounds__(256) void k_edge_fill(const int* __restrict__ src, const int* __restrict__ dst,
                                                   int* __restrict__ cursor, int* __restrict__ esrc, int E) {
  int stride = gridDim.x * blockDim.x;
  for (int e = blockIdx.x * blockDim.x + threadIdx.x; e < E; e += stride) {
    int s = src[e], d = dst[e];
    int pos = atomicAdd(&cursor[d], 1);
    esrc[pos] = s;
  }
}

// ---------------- W_c = W_out @ W1, b_c = b_out @ W1 ----------------

__global__ __launch_bounds__(256) void k_wc(const float* __restrict__ Wout, const float* __restrict__ bout,
                                            const float* __restrict__ W1, float* __restrict__ Wc,
                                            float* __restrict__ bc) {
  int t = blockIdx.x * 256 + threadIdx.x;
  if (t >= 65 * 128) return;
  int h = t >> 7, o = t & 127;
  const float* row = (h < 64) ? (Wout + h * 128) : bout;
  float a = 0.f;
  for (int d = 0; d < 128; ++d) a += row[d] * W1[d * 128 + o];
  if (h < 64) Wc[h * 128 + o] = a;
  else bc[o] = a;
}

// ---------------- attention pooling (X-stationary) ----------------
// Wave owns 60 consecutive set-rows = 3 nodes (lane = row; lanes 60-63 idle).
// Lane accumulates its row's z[64] in VGPRs; WE broadcast via wave-uniform
// loads -> inner loop is v_fmac at/near the VALU floor.

__global__ __launch_bounds__(256, 3) void k_pool(const float* __restrict__ X, const int* __restrict__ mask,
                                                 const float* __restrict__ WE, const float* __restrict__ bE,
                                                 const float* __restrict__ WA, const float* __restrict__ bA,
                                                 float* __restrict__ pz, int N) {
  __shared__ float lds_s[4][64];
  __shared__ float lds_z[4][64 * 20];
  const int lane = threadIdx.x & 63;
  const int wid = threadIdx.x >> 6;

  const long long totRows = (long long)N * 20;
  long long row = (long long)blockIdx.x * 240 + wid * 60 + lane;
  const float* __restrict__ xr = X + (row < totRows ? row : (totRows - 1)) * 128;

  float acc[64];
#pragma unroll
  for (int h = 0; h < 64; ++h) acc[h] = 0.f;

  float x[8], xn[8];
  *(float4*)&x[0] = *(const float4*)(xr + 0);
  *(float4*)&x[4] = *(const float4*)(xr + 4);

#pragma unroll 2
  for (int c = 0; c < 16; ++c) {
    const int cn = (c + 1) & 15;  // wrap: chunk-15 prefetches chunk-0 again (harmless, branch-free)
    *(float4*)&xn[0] = *(const float4*)(xr + cn * 8 + 0);
    *(float4*)&xn[4] = *(const float4*)(xr + cn * 8 + 4);
    const float* __restrict__ wp = WE + c * 8 * 64;
#pragma unroll
    for (int d = 0; d < 8; ++d) {
#pragma unroll
      for (int hq = 0; hq < 16; ++hq) {
        const float4 we = *(const float4*)(wp + d * 64 + hq * 4);  // wave-uniform
        acc[hq * 4 + 0] += we.x * x[d];
        acc[hq * 4 + 1] += we.y * x[d];
        acc[hq * 4 + 2] += we.z * x[d];
        acc[hq * 4 + 3] += we.w * x[d];
      }
    }
#pragma unroll
    for (int d = 0; d < 8; ++d) x[d] = xn[d];
  }

  // z = relu(acc + bE); score = z . WA + bA
  float sc = bA[0];
#pragma unroll
  for (int h = 0; h < 64; ++h) {
    float z = fmaxf(acc[h] + bE[h], 0.f);
    acc[h] = z;
    sc = fmaf(z, WA[h], sc);
  }

  const int ln = (lane < 60) ? (lane / 20) : 0;  // node-in-wave 0..2
  const int s_in = lane - ln * 20;
  const int node = blockIdx.x * 12 + wid * 3 + ln;
  const bool act = (lane < 60) && (node < N);
  const int mk = act ? mask[node * 20 + s_in] : 0;
  const float NEG = -3.0e38f;
  if (!act || mk == 0) sc = NEG;

  float* ss = &lds_s[wid][0];
  ss[lane] = sc;
  __syncthreads();
  float mx = NEG;
#pragma unroll
  for (int i = 0; i < 20; ++i) mx = fmaxf(mx, ss[ln * 20 + i]);
  const float p = (sc == NEG) ? 0.f : __expf(sc - mx);  // masked -> exactly 0, no NaN
  __syncthreads();
  ss[lane] = p;
  __syncthreads();
  float den = 0.f;
#pragma unroll
  for (int i = 0; i < 20; ++i) den += ss[ln * 20 + i];
  const float wgt = p / fmaxf(den, 1e-37f);  // dead groups: 0/eps = 0, no NaN
#pragma unroll
  for (int h = 0; h < 64; ++h) acc[h] *= wgt;

  // pooled[n][h] = sum over the node's 20 lanes of acc[h], via 16-col chunks
  float* zz = &lds_z[wid][0];
  const int on = lane >> 4;   // output node 0..2 (lane<48)
  const int oh = lane & 15;   // output h within chunk
  for (int ch = 0; ch < 4; ++ch) {
    __syncthreads();  // previous iteration's reads done before overwrite
    if (lane < 60) {
#pragma unroll
      for (int col = 0; col < 16; ++col) zz[lane * 20 + col] = acc[ch * 16 + col];
    }
    __syncthreads();
    if (lane < 48) {
      float o = 0.f;
#pragma unroll
      for (int s2 = 0; s2 < 20; ++s2) o += zz[(on * 20 + s2) * 20 + oh];
      const int outNode = blockIdx.x * 12 + wid * 3 + on;
      if (outNode < N) pz[(size_t)outNode * 64 + ch * 16 + oh] = o;
    }
  }
}

// ---------------- h1p = (pz @ Wc + bc) * dinv[r] ----------------

__global__ __launch_bounds__(256, 2) void k_gemm1(const float* __restrict__ pz, const float* __restrict__ Wc,
                                                  const float* __restrict__ bc, const float* __restrict__ dinv,
                                                  float* __restrict__ h1p, int N) {
  const int lane = threadIdx.x & 63;
  float w0[64], w1[64];
#pragma unroll
  for (int d = 0; d < 64; ++d) {
    w0[d] = Wc[d * 128 + lane];
    w1[d] = Wc[d * 128 + 64 + lane];
  }
  const float b0 = bc[lane], b1v = bc[64 + lane];
  const int nw = (gridDim.x * blockDim.x) >> 6;
  const int w_id = (blockIdx.x * blockDim.x + threadIdx.x) >> 6;
  for (int r = w_id; r < N; r += nw) {
    const float xv = pz[(size_t)r * 64 + lane];
    const int xi = __float_as_int(xv);
    float p0 = 0.f, p1 = 0.f, p2 = 0.f, p3 = 0.f;
#pragma unroll
    for (int d0 = 0; d0 < 64; d0 += 2) {
      float a0 = RL((float&)xi, d0);
      float a1 = RL((float&)xi, d0 + 1);
      p0 += a0 * w0[d0];
      p1 += a0 * w1[d0];
      p2 += a1 * w0[d0 + 1];
      p3 += a1 * w1[d0 + 1];
    }
    float di = dinv[r];
    size_t o = (size_t)r * 128 + lane;
    h1p[o] = (b0 + p0 + p2) * di;
    h1p[o + 64] = (b1v + p1 + p3) * di;
  }
}

// ---------------- gather layer 1: x1[d] = dinv[d]*(sum_in h1p[s] + h1p[d]*dinv[d]) ----------------
// one wave per dst node; two 32-lane halves take alternate edges (4-deep each
// -> 8 float4 gathers in flight/wave); combine via shfl_xor(32).

__global__ __launch_bounds__(256) void k_gather1(const int* __restrict__ row, const int* __restrict__ cnt,
                                                 const int* __restrict__ esrc, const float* __restrict__ h1p,
                                                 const float* __restrict__ dinv, float* __restrict__ x1, int N) {
  const int lane = threadIdx.x & 63;
  const int node = RFL(blockIdx.x * 4 + (threadIdx.x >> 6));
  if (node >= N) return;
  const int half = lane >> 5, f4 = lane & 31;
  const int rs = RFL(row[node]);
  const int ne = RFL(cnt[node]);
  const float di = dinv[node];
  const float4* __restrict__ hv = (const float4*)h1p;
  float a0 = 0.f, a1 = 0.f, a2 = 0.f, a3 = 0.f;
  int j = half;
  for (; j + 7 <= ne; j += 8) {  // edges j, j+2, j+4, j+6 for this half
    int s0 = esrc[rs + j], s1 = esrc[rs + j + 2], s2 = esrc[rs + j + 4], s3 = esrc[rs + j + 6];
    float4 v0 = hv[(size_t)s0 * 32 + f4];
    float4 v1 = hv[(size_t)s1 * 32 + f4];
    float4 v2 = hv[(size_t)s2 * 32 + f4];
    float4 v3 = hv[(size_t)s3 * 32 + f4];
    a0 += v0.x + v1.x + v2.x + v3.x;
    a1 += v0.y + v1.y + v2.y + v3.y;
    a2 += v0.z + v1.z + v2.z + v3.z;
    a3 += v0.w + v1.w + v2.w + v3.w;
  }
  for (; j < ne; j += 2) {
    int s = esrc[rs + j];
    float4 v = hv[(size_t)s * 32 + f4];
    a0 += v.x; a1 += v.y; a2 += v.z; a3 += v.w;
  }
  a0 += __shfl_xor(a0, 32, 64);
  a1 += __shfl_xor(a1, 32, 64);
  a2 += __shfl_xor(a2, 32, 64);
  a3 += __shfl_xor(a3, 32, 64);
  if (half == 0) {
    float4 sv = hv[(size_t)node * 32 + f4];
    float4 o;
    o.x = (a0 + sv.x * di) * di;
    o.y = (a1 + sv.y * di) * di;
    o.z = (a2 + sv.z * di) * di;
    o.w = (a3 + sv.w * di) * di;
    ((float4*)x1)[(size_t)node * 32 + f4] = o;
  }
}

// ---------------- h2p = (relu(x1 + b1) @ W2) * dinv[r] ----------------

__global__ __launch_bounds__(256, 2) void k_gemm2(const float* __restrict__ x1, const float* __restrict__ b1,
                                                  const float* __restrict__ W2, const float* __restrict__ dinv,
                                                  float* __restrict__ h2p, int N) {
  const int lane = threadIdx.x & 63;
  const int col = lane & 31;
  float w[128];
#pragma unroll
  for (int d = 0; d < 128; ++d) w[d] = W2[d * 32 + col];
  const float bb0 = b1[lane], bb1 = b1[64 + lane];
  const int nw = (gridDim.x * blockDim.x) >> 6;
  const int w_id = (blockIdx.x * blockDim.x + threadIdx.x) >> 6;
  for (int r = w_id; r < N; r += nw) {
    float rx0 = fmaxf(x1[(size_t)r * 128 + lane] + bb0, 0.f);
    float rx1 = fmaxf(x1[(size_t)r * 128 + 64 + lane] + bb1, 0.f);
    const int xi0 = __float_as_int(rx0), xi1 = __float_as_int(rx1);
    float p0 = 0.f, p1 = 0.f, p2 = 0.f, p3 = 0.f;
#pragma unroll
    for (int d0 = 0; d0 < 64; d0 += 2) {
      float a0 = RL((float&)xi0, d0);
      float a1 = RL((float&)xi0, d0 + 1);
      float c0 = RL((float&)xi1, d0);
      float c1 = RL((float&)xi1, d0 + 1);
      p0 += a0 * w[d0];
      p1 += a1 * w[d0 + 1];
      p2 += c0 * w[64 + d0];
      p3 += c1 * w[64 + d0 + 1];
    }
    if (lane < 32) {
      float di = dinv[r];
      h2p[(size_t)r * 32 + col] = ((p0 + p1) + (p2 + p3)) * di;
    }
  }
}

// ---------------- gather layer 2: 8 groups of 8 lanes (float4), 2-deep ----------------
// 16 edges in flight per wave; combine via shfl_xor 8/16/32.

__global__ __launch_bounds__(256) void k_gather2(const int* __restrict__ row, const int* __restrict__ cnt,
                                                 const int* __restrict__ esrc, const float* __restrict__ h2p,
                                                 const float* __restrict__ dinv, float* __restrict__ x2, int N) {
  const int lane = threadIdx.x & 63;
  const int node = RFL(blockIdx.x * 4 + (threadIdx.x >> 6));
  if (node >= N) return;
  const int q = lane >> 3, f4 = lane & 7;  // group 0..7, float4 slot 0..7 (8x4=32 floats)
  const int rs = RFL(row[node]);
  const int ne = RFL(cnt[node]);
  const float di = dinv[node];
  const float4* __restrict__ hv = (const float4*)h2p;
  float a0 = 0.f, a1 = 0.f, a2 = 0.f, a3 = 0.f;
  int j = q;
  for (; j + 9 <= ne; j += 16) {  // edges j and j+8 for this group
    int s0 = esrc[rs + j], s1 = esrc[rs + j + 8];
    float4 v0 = hv[(size_t)s0 * 8 + f4];
    float4 v1 = hv[(size_t)s1 * 8 + f4];
    a0 += v0.x + v1.x;
    a1 += v0.y + v1.y;
    a2 += v0.z + v1.z;
    a3 += v0.w + v1.w;
  }
  for (; j < ne; j += 8) {
    int s = esrc[rs + j];
    float4 v = hv[(size_t)s * 8 + f4];
    a0 += v.x; a1 += v.y; a2 += v.z; a3 += v.w;
  }
#pragma unroll
  for (int off = 8; off <= 32; off <<= 1) {
    a0 += __shfl_xor(a0, off, 64);
    a1 += __shfl_xor(a1, off, 64);
    a2 += __shfl_xor(a2, off, 64);
    a3 += __shfl_xor(a3, off, 64);
  }
  if (q == 0) {
    float4 sv = hv[(size_t)node * 8 + f4];
    float4 o;
    o.x = (a0 + sv.x * di) * di;
    o.y = (a1 + sv.y * di) * di;
    o.z = (a2 + sv.z * di) * di;
    o.w = (a3 + sv.w * di) * di;
    ((float4*)x2)[(size_t)node * 8 + f4] = o;
  }
}

// ---------------- query MLP ----------------

__global__ __launch_bounds__(256) void k_mlp(const int* __restrict__ qidx, const float* __restrict__ x2,
                                             const float* __restrict__ b2, const float* __restrict__ Wm1,
                                             const float* __restrict__ bm1, const float* __restrict__ Wm2,
                                             const float* __restrict__ bm2, float* __restrict__ out, int B) {
  int t = blockIdx.x * 256 + threadIdx.x;
  if (t >= B) return;
  int n = qidx[t];
  float qv[32];
#pragma unroll
  for (int k = 0; k < 32; ++k) qv[k] = fmaxf(x2[(size_t)n * 32 + k] + b2[k], 0.f);
  float acc = bm2[0];
  for (int j = 0; j < 64; ++j) {
    float h = bm1[j];
#pragma unroll
    for (int k = 0; k < 32; ++k) h += qv[k] * Wm1[k * 64 + j];
    acc += fmaxf(h, 0.f) * Wm2[j];
  }
  out[t] = acc;
}

// ---------------- launcher ----------------

extern "C" void kernel_launch(void* const* d_in, const int* in_sizes, int n_in,
                              void* d_out, int out_size, void* d_ws, size_t ws_size,
                              hipStream_t stream) {
  const float* X    = (const float*)d_in[0];
  const int*   mask = (const int*)d_in[1];
  const int*   ei   = (const int*)d_in[2];
  const int*   qidx = (const int*)d_in[3];
  const float* WE   = (const float*)d_in[4];
  const float* bE   = (const float*)d_in[5];
  const float* WA   = (const float*)d_in[6];
  const float* bA   = (const float*)d_in[7];
  const float* Wout = (const float*)d_in[8];
  const float* bout = (const float*)d_in[9];
  const float* W1   = (const float*)d_in[10];
  const float* b1   = (const float*)d_in[11];
  const float* W2   = (const float*)d_in[12];
  const float* b2   = (const float*)d_in[13];
  const float* Wm1  = (const float*)d_in[14];
  const float* bm1  = (const float*)d_in[15];
  const float* Wm2  = (const float*)d_in[16];
  const float* bm2  = (const float*)d_in[17];

  const int N = in_sizes[1] / 20;
  const int E = in_sizes[2] / 2;
  const int B = in_sizes[3];
  const int* src  = ei;
  const int* dstp = ei + E;

  const size_t Na = ((size_t)N + 63) & ~(size_t)63;
  const size_t Ea = ((size_t)E + 63) & ~(size_t)63;
  const int P = (N + 255) / 256;
  const size_t Pa = ((size_t)P + 63) & ~(size_t)63;

  float* ws      = (float*)d_ws;
  float* dinv    = ws;                       // N
  int*   cnt     = (int*)(dinv + Na);        // N
  int*   rowp    = cnt + Na;                 // N
  int*   cursor  = rowp + Na;                // N
  int*   partial = cursor + Na;              // P
  int*   esrc    = partial + Pa;             // E
  float* Wc      = (float*)(esrc + Ea);      // 8192
  float* bc      = Wc + 8192;                // 128
  float* pz      = bc + 128;                 // N*64
  float* h1p     = pz + (size_t)N * 64;      // N*128
  float* x1      = h1p + (size_t)N * 128;    // N*128
  float* h2p     = pz;                       // reuse pz (dead after gemm1): N*32
  float* x2      = pz + (size_t)N * 32;      // N*32

  const int nb = (N + 255) / 256;
  const int nw4 = (N + 3) / 4;
  const int nw12 = (N + 11) / 12;

  k_zero<<<nb, 256, 0, stream>>>(cnt, N);
  k_count<<<1024, 256, 0, stream>>>(dstp, cnt, E);
  k_scan1<<<P, 256, 0, stream>>>(cnt, rowp, partial, N);
  k_scan2<<<1, 256, 0, stream>>>(partial, P);
  k_scan3<<<P, 256, 0, stream>>>(rowp, partial, cursor, cnt, dinv, N);
  k_edge_fill<<<1024, 256, 0, stream>>>(src, dstp, cursor, esrc, E);
  k_wc<<<33, 256, 0, stream>>>(Wout, bout, W1, Wc, bc);
  k_pool<<<nw12, 256, 0, stream>>>(X, mask, WE, bE, WA, bA, pz, N);
  k_gemm1<<<1024, 256, 0, stream>>>(pz, Wc, bc, dinv, h1p, N);
  k_gather1<<<nw4, 256, 0, stream>>>(rowp, cnt, esrc, h1p, dinv, x1, N);
  k_gemm2<<<1024, 256, 0, stream>>>(x1, b1, W2, dinv, h2p, N);
  k_gather2<<<nw4, 256, 0, stream>>>(rowp, cnt, esrc, h2p, dinv, x2, N);
  k_mlp<<<(B + 255) / 256, 256, 0, stream>>>(qidx, x2, b2, Wm1, bm1, Wm2, bm2, (float*)d_out, B);
}